// Round 16
// baseline (117.537 us; speedup 1.0000x reference)
//
#include <hip/hip_runtime.h>
#include <hip/hip_bf16.h>

#define NSTEPS 20
#define BROWS  8192
#define LATENT 256
#define UDIM   16
#define HIDDEN 512
#define BM     32      // rows per block
#define XLD    296     // LDS row stride (bf16) for X
#define HLD    536     // LDS row stride (bf16) for H
#define NKC    3       // W1 kt-tiles cached in LDS (kt = 0..NKC-1)

// packed-weight footprint (shorts)
#define W1P_SHORTS (9 * 32 * 64 * 8)     // 147456
#define W2P_SHORTS (16 * 16 * 64 * 8)    // 131072

// Packed weights in module-scope device memory; re-packed from immutable
// W1/W2 every call -> deterministic across graph replays.
__device__ __align__(16) short g_Wpack[W1P_SHORTS + W2P_SHORTS];

typedef __attribute__((ext_vector_type(8))) short bf16x8;
typedef __attribute__((ext_vector_type(4))) short bf16x4;
typedef __attribute__((ext_vector_type(4))) float f32x4;

typedef __attribute__((address_space(1))) const unsigned int gbl_u32;
typedef __attribute__((address_space(3))) unsigned int lds_u32;

__device__ __forceinline__ short f2bf(float x) {
    union { __hip_bfloat16 h; short s; } u;
    u.h = __float2bfloat16(x);
    return u.s;
}

__device__ __forceinline__ float tanh_fast(float x) {
    float e = __expf(2.0f * x);
    return 1.0f - 2.0f * __builtin_amdgcn_rcpf(e + 1.0f);
}

// raw barrier: drains LDS ops only; leaves the global-load queue alive
__device__ __forceinline__ void lds_barrier() {
    asm volatile("s_waitcnt lgkmcnt(0)" ::: "memory");
    __builtin_amdgcn_s_barrier();
}

__device__ __forceinline__ const bf16x8* w1_frag(const short* W1p, int kt, int nt, int l) {
    return reinterpret_cast<const bf16x8*>(W1p + ((kt * 32 + nt) * 64 + l) * 8);
}
__device__ __forceinline__ const bf16x8* w2_frag(const short* W2p, int kt2, int nt, int l) {
    return reinterpret_cast<const bf16x8*>(W2p + ((kt2 * 16 + nt) * 64 + l) * 8);
}

// Pack W1 (272x512, K zero-padded to 288) and W2 (512x256) into per-fragment
// order: frag(kt,nt): lane l holds W[k = kt*32 + (l>>4)*8 + j][n = nt*16 + (l&15)].
__global__ void prep_weights(const float* __restrict__ W1, const float* __restrict__ W2) {
    short* W1p = g_Wpack;
    short* W2p = g_Wpack + W1P_SHORTS;
    int t = blockIdx.x * 256 + threadIdx.x;
    if (t < 9 * 32 * 64) {
        int l = t & 63, f = t >> 6;          // f: 0..287 = kt*32+nt
        int kt = f >> 5, nt = f & 31;
        int k0 = kt * 32 + ((l >> 4) << 3);
        int n = nt * 16 + (l & 15);
        bf16x8 o;
#pragma unroll
        for (int j = 0; j < 8; ++j) {
            int k = k0 + j;
            o[j] = (k < 272) ? f2bf(W1[k * 512 + n]) : (short)0;
        }
        *reinterpret_cast<bf16x8*>(W1p + t * 8) = o;
    } else if (t < 9 * 32 * 64 + 16 * 16 * 64) {
        int t2 = t - 9 * 32 * 64;
        int l = t2 & 63, f = t2 >> 6;        // f: 0..255 = kt*16+nt
        int kt = f >> 4, nt = f & 15;
        int k0 = kt * 32 + ((l >> 4) << 3);
        int n = nt * 16 + (l & 15);
        bf16x8 o;
#pragma unroll
        for (int j = 0; j < 8; ++j) o[j] = f2bf(W2[(k0 + j) * 256 + n]);
        *reinterpret_cast<bf16x8*>(W2p + t2 * 8) = o;
    }
}

// r16: r15 (W1c cache kt0-2 + global->VGPR streams) with the prefetch issues
// MOVED into the port-idle windows:
//  - W1 kt3/kt4 issue right after GEMM2's MFMAs -> stream during z-update +
//    X-write + barrier (was: after the barrier, colliding with GEMM1 start).
//  - W2 kt2=0,1 issue before tanh (unchanged) -> stream during tanh+barrier.
// In-loop +2-ahead refills unchanged. No new buffers (VGPR wall at 128).
__global__ __launch_bounds__(512, 2) void ode_kernel(
    const float* __restrict__ zt, const float* __restrict__ dtp,
    const float* __restrict__ ut, const float* __restrict__ b1,
    const float* __restrict__ b2, float* __restrict__ out) {
    __shared__ __align__(16) short X[BM * XLD];            // 18,944 B
    __shared__ __align__(16) short H[BM * HLD];            // 34,304 B
    __shared__ __align__(16) short W1c[8][NKC][4][512];    // 98,304 B (151,552 total)

    const short* W1p = g_Wpack;
    const short* W2p = g_Wpack + W1P_SHORTS;

    const int tid = threadIdx.x;
    const int w = tid >> 6;          // wave 0..7
    const int l = tid & 63;
    const int l16 = l & 15;
    const int lg = l >> 4;           // 0..3
    const int row0 = blockIdx.x * BM;

    // stage the persistent W1 cache FIRST (12 gload_lds per wave, no VGPR dest)
#pragma unroll
    for (int kt = 0; kt < NKC; ++kt)
#pragma unroll
        for (int j = 0; j < 4; ++j)
            __builtin_amdgcn_global_load_lds(
                (gbl_u32*)w1_frag(W1p, kt, w * 4 + j, l),
                (lds_u32*)&W1c[w][kt][j][0], 16, 0, 0);

    float b1v[4], b2v[2];
#pragma unroll
    for (int j = 0; j < 4; ++j) b1v[j] = b1[(w * 4 + j) * 16 + l16];
#pragma unroll
    for (int j = 0; j < 2; ++j) b2v[j] = b2[(w * 2 + j) * 16 + l16];

    float hstep[2];
#pragma unroll
    for (int mt = 0; mt < 2; ++mt)
        hstep[mt] = dtp[row0 + mt * 16 + l16] * (1.0f / NSTEPS);

    f32x4 z[2][2];
#pragma unroll
    for (int mt = 0; mt < 2; ++mt)
#pragma unroll
        for (int j2 = 0; j2 < 2; ++j2)
            z[mt][j2] = *reinterpret_cast<const f32x4*>(
                &zt[(row0 + mt * 16 + l16) * LATENT + (w * 2 + j2) * 16 + lg * 4]);

    {
        int r = tid >> 4, c = tid & 15;   // 512 threads = 32 rows x 16 cols
        X[r * XLD + 256 + c] = f2bf(ut[(row0 + r) * UDIM + c]);
        X[r * XLD + 272 + c] = 0;
    }
#pragma unroll
    for (int mt = 0; mt < 2; ++mt)
#pragma unroll
        for (int j2 = 0; j2 < 2; ++j2) {
            bf16x4 p;
#pragma unroll
            for (int i = 0; i < 4; ++i) p[i] = f2bf(z[mt][j2][i]);
            *reinterpret_cast<bf16x4*>(&X[(mt * 16 + l16) * XLD + (w * 2 + j2) * 16 + lg * 4]) = p;
        }

    bf16x8 wf[2][4];     // streamed-W1 double buffer (kt = 3..8)
    bf16x8 w2b[2][2];    // streamed-W2 double buffer

    // step-0 prologue: kt3/kt4 in flight across the init barrier
#pragma unroll
    for (int j = 0; j < 4; ++j) wf[1][j] = *w1_frag(W1p, 3, w * 4 + j, l);
#pragma unroll
    for (int j = 0; j < 4; ++j) wf[0][j] = *w1_frag(W1p, 4, w * 4 + j, l);
    __builtin_amdgcn_sched_barrier(0);

    lds_barrier();

#pragma unroll 1
    for (int t = 0; t < NSTEPS; ++t) {
        // ---- GEMM1: hidden^T = W1^T x X^T, K = 288 (kt 0..2 LDS, 3..8 stream)
        f32x4 acc1[2][4];
#pragma unroll
        for (int mt = 0; mt < 2; ++mt)
#pragma unroll
            for (int j = 0; j < 4; ++j)
                acc1[mt][j] = (f32x4){b1v[j], b1v[j], b1v[j], b1v[j]};

#pragma unroll
        for (int kt = 0; kt < 9; ++kt) {
            bf16x8 a[4];
            if (kt < NKC) {
#pragma unroll
                for (int j = 0; j < 4; ++j)
                    a[j] = *reinterpret_cast<const bf16x8*>(&W1c[w][kt][j][l * 8]);
            } else {
#pragma unroll
                for (int j = 0; j < 4; ++j) a[j] = wf[kt & 1][j];
            }
            bf16x8 xb0 = *reinterpret_cast<const bf16x8*>(&X[(0 * 16 + l16) * XLD + kt * 32 + lg * 8]);
            bf16x8 xb1 = *reinterpret_cast<const bf16x8*>(&X[(1 * 16 + l16) * XLD + kt * 32 + lg * 8]);
#pragma unroll
            for (int j = 0; j < 4; ++j) {
                acc1[0][j] = __builtin_amdgcn_mfma_f32_16x16x32_bf16(a[j], xb0, acc1[0][j], 0, 0, 0);
                acc1[1][j] = __builtin_amdgcn_mfma_f32_16x16x32_bf16(a[j], xb1, acc1[1][j], 0, 0, 0);
            }
            __builtin_amdgcn_sched_barrier(0);
            if (kt >= 3 && kt + 2 < 9) {   // refill the just-consumed buffer with kt+2
#pragma unroll
                for (int j = 0; j < 4; ++j)
                    wf[kt & 1][j] = *w1_frag(W1p, kt + 2, w * 4 + j, l);
            }
        }

        // GEMM2 prologue: kt2=0,1 issue now; latency hides under tanh + barrier
#pragma unroll
        for (int j2 = 0; j2 < 2; ++j2) {
            w2b[0][j2] = *w2_frag(W2p, 0, w * 2 + j2, l);
            w2b[1][j2] = *w2_frag(W2p, 1, w * 2 + j2, l);
        }
        __builtin_amdgcn_sched_barrier(0);

        // tanh + pack hidden into LDS
#pragma unroll
        for (int mt = 0; mt < 2; ++mt)
#pragma unroll
            for (int j = 0; j < 4; ++j) {
                bf16x4 p;
#pragma unroll
                for (int i = 0; i < 4; ++i) p[i] = f2bf(tanh_fast(acc1[mt][j][i]));
                *reinterpret_cast<bf16x4*>(&H[(mt * 16 + l16) * HLD + (w * 4 + j) * 16 + lg * 4]) = p;
            }
        lds_barrier();   // lgkm-only: weight loads stay in flight

        // ---- GEMM2: f^T = W2^T (VGPR stream, 2-ahead) x hidden^T (LDS), K = 512
        f32x4 acc2[2][2];
#pragma unroll
        for (int mt = 0; mt < 2; ++mt)
#pragma unroll
            for (int j2 = 0; j2 < 2; ++j2)
                acc2[mt][j2] = (f32x4){b2v[j2], b2v[j2], b2v[j2], b2v[j2]};

#pragma unroll
        for (int kt2 = 0; kt2 < 16; ++kt2) {
            bf16x8 hb0 = *reinterpret_cast<const bf16x8*>(&H[(0 * 16 + l16) * HLD + kt2 * 32 + lg * 8]);
            bf16x8 hb1 = *reinterpret_cast<const bf16x8*>(&H[(1 * 16 + l16) * HLD + kt2 * 32 + lg * 8]);
#pragma unroll
            for (int j2 = 0; j2 < 2; ++j2) {
                acc2[0][j2] = __builtin_amdgcn_mfma_f32_16x16x32_bf16(w2b[kt2 & 1][j2], hb0, acc2[0][j2], 0, 0, 0);
                acc2[1][j2] = __builtin_amdgcn_mfma_f32_16x16x32_bf16(w2b[kt2 & 1][j2], hb1, acc2[1][j2], 0, 0, 0);
            }
            __builtin_amdgcn_sched_barrier(0);
            if (kt2 + 2 < 16) {   // refill the just-consumed buffer with kt2+2
#pragma unroll
                for (int j2 = 0; j2 < 2; ++j2)
                    w2b[kt2 & 1][j2] = *w2_frag(W2p, kt2 + 2, w * 2 + j2, l);
            }
        }

        // next step's W1 kt3/kt4: issue NOW so they stream during the
        // z-update + X-write + barrier window (port was idle here in r15).
        // Unconditional: dead at t=19, harmless.
#pragma unroll
        for (int j = 0; j < 4; ++j) wf[1][j] = *w1_frag(W1p, 3, w * 4 + j, l);
#pragma unroll
        for (int j = 0; j < 4; ++j) wf[0][j] = *w1_frag(W1p, 4, w * 4 + j, l);
        __builtin_amdgcn_sched_barrier(0);

        // z += h * f ; write z back to X (bf16) for next step
#pragma unroll
        for (int mt = 0; mt < 2; ++mt)
#pragma unroll
            for (int j2 = 0; j2 < 2; ++j2)
#pragma unroll
                for (int i = 0; i < 4; ++i)
                    z[mt][j2][i] += hstep[mt] * acc2[mt][j2][i];

        if (t < NSTEPS - 1) {
#pragma unroll
            for (int mt = 0; mt < 2; ++mt)
#pragma unroll
                for (int j2 = 0; j2 < 2; ++j2) {
                    bf16x4 p;
#pragma unroll
                    for (int i = 0; i < 4; ++i) p[i] = f2bf(z[mt][j2][i]);
                    *reinterpret_cast<bf16x4*>(&X[(mt * 16 + l16) * XLD + (w * 2 + j2) * 16 + lg * 4]) = p;
                }
            lds_barrier();
        }
    }

    // final store (f32)
#pragma unroll
    for (int mt = 0; mt < 2; ++mt)
#pragma unroll
        for (int j2 = 0; j2 < 2; ++j2)
            *reinterpret_cast<f32x4*>(
                &out[(row0 + mt * 16 + l16) * LATENT + (w * 2 + j2) * 16 + lg * 4]) = z[mt][j2];
}

extern "C" void kernel_launch(void* const* d_in, const int* in_sizes, int n_in,
                              void* d_out, int out_size, void* d_ws, size_t ws_size,
                              hipStream_t stream) {
    const float* zt = (const float*)d_in[0];
    const float* dtp = (const float*)d_in[1];
    const float* ut = (const float*)d_in[2];
    const float* W1 = (const float*)d_in[3];
    const float* b1 = (const float*)d_in[4];
    const float* W2 = (const float*)d_in[5];
    const float* b2 = (const float*)d_in[6];

    prep_weights<<<136, 256, 0, stream>>>(W1, W2);
    ode_kernel<<<BROWS / BM, 512, 0, stream>>>(zt, dtp, ut, b1, b2, (float*)d_out);
}

// Round 17
// 105.096 us; speedup vs baseline: 1.1184x; 1.1184x over previous
//
#include <hip/hip_runtime.h>
#include <hip/hip_bf16.h>

#define NSTEPS 20
#define BROWS  8192
#define LATENT 256
#define UDIM   16
#define HIDDEN 512
#define BM     32      // rows per block
#define XLD    296     // LDS row stride (bf16) for X
#define HLD8   528     // LDS row stride (BYTES) for fp8 H (2-way free on b32/b64)
#define NKC    3       // W1 kt-tiles cached in LDS (kt = 0..NKC-1)

// packed-weight footprint
#define W1P_SHORTS (9 * 32 * 64 * 8)     // 147456 shorts (294912 B), bf16
#define W2P8_BYTES (16 * 16 * 64 * 8)    // 131072 B, fp8 e4m3

// Packed weights in module-scope device memory; re-packed from immutable
// W1/W2 every call -> deterministic across graph replays.
__device__ __align__(16) short g_Wpack[W1P_SHORTS + W2P8_BYTES / 2];

typedef __attribute__((ext_vector_type(8))) short bf16x8;
typedef __attribute__((ext_vector_type(4))) short bf16x4;
typedef __attribute__((ext_vector_type(4))) float f32x4;
typedef __attribute__((ext_vector_type(2))) unsigned int u32x2;

typedef __attribute__((address_space(1))) const unsigned int gbl_u32;
typedef __attribute__((address_space(3))) unsigned int lds_u32;

__device__ __forceinline__ short f2bf(float x) {
    union { __hip_bfloat16 h; short s; } u;
    u.h = __float2bfloat16(x);
    return u.s;
}

__device__ __forceinline__ long as_i64(u32x2 v) {
    union { u32x2 v; long l; } u; u.v = v; return u.l;
}

__device__ __forceinline__ float tanh_fast(float x) {
    float e = __expf(2.0f * x);
    return 1.0f - 2.0f * __builtin_amdgcn_rcpf(e + 1.0f);
}

// raw barrier: drains LDS ops only; leaves the global-load queue alive
__device__ __forceinline__ void lds_barrier() {
    asm volatile("s_waitcnt lgkmcnt(0)" ::: "memory");
    __builtin_amdgcn_s_barrier();
}

__device__ __forceinline__ const bf16x8* w1_frag(const short* W1p, int kt, int nt, int l) {
    return reinterpret_cast<const bf16x8*>(W1p + ((kt * 32 + nt) * 64 + l) * 8);
}
__device__ __forceinline__ const u32x2* w2_frag8(const unsigned char* W2p8, int kt2, int nt, int l) {
    return reinterpret_cast<const u32x2*>(W2p8 + ((kt2 * 16 + nt) * 64 + l) * 8);
}

// Pack W1 (272x512, K zero-padded to 288) as bf16 and W2 (512x256) as fp8
// e4m3 into per-fragment order: frag(kt,nt): lane l holds
// W[k = kt*32 + (l>>4)*8 + j][n = nt*16 + (l&15)], j=0..7.
__global__ void prep_weights(const float* __restrict__ W1, const float* __restrict__ W2) {
    short* W1p = g_Wpack;
    unsigned char* W2p8 = (unsigned char*)(g_Wpack + W1P_SHORTS);
    int t = blockIdx.x * 256 + threadIdx.x;
    if (t < 9 * 32 * 64) {
        int l = t & 63, f = t >> 6;          // f: 0..287 = kt*32+nt
        int kt = f >> 5, nt = f & 31;
        int k0 = kt * 32 + ((l >> 4) << 3);
        int n = nt * 16 + (l & 15);
        bf16x8 o;
#pragma unroll
        for (int j = 0; j < 8; ++j) {
            int k = k0 + j;
            o[j] = (k < 272) ? f2bf(W1[k * 512 + n]) : (short)0;
        }
        *reinterpret_cast<bf16x8*>(W1p + t * 8) = o;
    } else if (t < 9 * 32 * 64 + 16 * 16 * 64) {
        int t2 = t - 9 * 32 * 64;
        int l = t2 & 63, f = t2 >> 6;        // f: 0..255 = kt*16+nt
        int kt = f >> 4, nt = f & 15;
        int k0 = kt * 32 + ((l >> 4) << 3);
        int n = nt * 16 + (l & 15);
        float v[8];
#pragma unroll
        for (int j = 0; j < 8; ++j) v[j] = W2[(k0 + j) * 256 + n];
        int d0 = 0, d1 = 0;
        d0 = __builtin_amdgcn_cvt_pk_fp8_f32(v[0], v[1], d0, 0);
        d0 = __builtin_amdgcn_cvt_pk_fp8_f32(v[2], v[3], d0, 1);
        d1 = __builtin_amdgcn_cvt_pk_fp8_f32(v[4], v[5], d1, 0);
        d1 = __builtin_amdgcn_cvt_pk_fp8_f32(v[6], v[7], d1, 1);
        *reinterpret_cast<u32x2*>(W2p8 + t2 * 8) = (u32x2){(unsigned)d0, (unsigned)d1};
    }
}

// r17: r15's best structure (W1c LDS cache kt0-2, global->VGPR streams with
// r15's issue placement) + GEMM2 moved to fp8: W2 streamed as e4m3 (128 KB vs
// 256 KB/step/CU) and H stored in LDS as e4m3 (b32 writes, b64 reads).
// Streamed bytes/step/CU: 448 -> 320 KB. f feeds z += h*f (h<=0.05), so the
// fp8 quantization error is attenuated by sum(h) = dt <= 1: est +0.02..0.04
// absmax on top of 0.031, vs threshold 0.114.
__global__ __launch_bounds__(512, 2) void ode_kernel(
    const float* __restrict__ zt, const float* __restrict__ dtp,
    const float* __restrict__ ut, const float* __restrict__ b1,
    const float* __restrict__ b2, float* __restrict__ out) {
    __shared__ __align__(16) short X[BM * XLD];             // 18,944 B
    __shared__ __align__(16) unsigned char H8[BM * HLD8];   // 16,896 B
    __shared__ __align__(16) short W1c[8][NKC][4][512];     // 98,304 B (134,144 total)

    const short* W1p = g_Wpack;
    const unsigned char* W2p8 = (const unsigned char*)(g_Wpack + W1P_SHORTS);

    const int tid = threadIdx.x;
    const int w = tid >> 6;          // wave 0..7
    const int l = tid & 63;
    const int l16 = l & 15;
    const int lg = l >> 4;           // 0..3
    const int row0 = blockIdx.x * BM;

    // stage the persistent W1 cache FIRST (12 gload_lds per wave, no VGPR dest)
#pragma unroll
    for (int kt = 0; kt < NKC; ++kt)
#pragma unroll
        for (int j = 0; j < 4; ++j)
            __builtin_amdgcn_global_load_lds(
                (gbl_u32*)w1_frag(W1p, kt, w * 4 + j, l),
                (lds_u32*)&W1c[w][kt][j][0], 16, 0, 0);

    float b1v[4], b2v[2];
#pragma unroll
    for (int j = 0; j < 4; ++j) b1v[j] = b1[(w * 4 + j) * 16 + l16];
#pragma unroll
    for (int j = 0; j < 2; ++j) b2v[j] = b2[(w * 2 + j) * 16 + l16];

    float hstep[2];
#pragma unroll
    for (int mt = 0; mt < 2; ++mt)
        hstep[mt] = dtp[row0 + mt * 16 + l16] * (1.0f / NSTEPS);

    f32x4 z[2][2];
#pragma unroll
    for (int mt = 0; mt < 2; ++mt)
#pragma unroll
        for (int j2 = 0; j2 < 2; ++j2)
            z[mt][j2] = *reinterpret_cast<const f32x4*>(
                &zt[(row0 + mt * 16 + l16) * LATENT + (w * 2 + j2) * 16 + lg * 4]);

    {
        int r = tid >> 4, c = tid & 15;   // 512 threads = 32 rows x 16 cols
        X[r * XLD + 256 + c] = f2bf(ut[(row0 + r) * UDIM + c]);
        X[r * XLD + 272 + c] = 0;
    }
#pragma unroll
    for (int mt = 0; mt < 2; ++mt)
#pragma unroll
        for (int j2 = 0; j2 < 2; ++j2) {
            bf16x4 p;
#pragma unroll
            for (int i = 0; i < 4; ++i) p[i] = f2bf(z[mt][j2][i]);
            *reinterpret_cast<bf16x4*>(&X[(mt * 16 + l16) * XLD + (w * 2 + j2) * 16 + lg * 4]) = p;
        }

    // W1c staged + all scalar loads done before the loop
    asm volatile("s_waitcnt vmcnt(0)" ::: "memory");
    lds_barrier();

    bf16x8 wf[2][4];     // streamed-W1 double buffer (kt = 3..8), bf16
    u32x2 w2b[2][2];     // streamed-W2 double buffer, fp8 (2 VGPR each)

#pragma unroll 1
    for (int t = 0; t < NSTEPS; ++t) {
        // ---- GEMM1: hidden^T = W1^T x X^T, K = 288 (kt 0..2 LDS, 3..8 stream)
        f32x4 acc1[2][4];
#pragma unroll
        for (int mt = 0; mt < 2; ++mt)
#pragma unroll
            for (int j = 0; j < 4; ++j)
                acc1[mt][j] = (f32x4){b1v[j], b1v[j], b1v[j], b1v[j]};

#pragma unroll
        for (int kt = 0; kt < 9; ++kt) {
            if (kt == 0) {   // kt=3's frags: 3-iteration lead (r15 placement)
#pragma unroll
                for (int j = 0; j < 4; ++j) wf[1][j] = *w1_frag(W1p, 3, w * 4 + j, l);
            }
            if (kt == 2) {   // kt=4's frags: 2-iteration lead
#pragma unroll
                for (int j = 0; j < 4; ++j) wf[0][j] = *w1_frag(W1p, 4, w * 4 + j, l);
            }
            __builtin_amdgcn_sched_barrier(0);
            bf16x8 a[4];
            if (kt < NKC) {
#pragma unroll
                for (int j = 0; j < 4; ++j)
                    a[j] = *reinterpret_cast<const bf16x8*>(&W1c[w][kt][j][l * 8]);
            } else {
#pragma unroll
                for (int j = 0; j < 4; ++j) a[j] = wf[kt & 1][j];
            }
            bf16x8 xb0 = *reinterpret_cast<const bf16x8*>(&X[(0 * 16 + l16) * XLD + kt * 32 + lg * 8]);
            bf16x8 xb1 = *reinterpret_cast<const bf16x8*>(&X[(1 * 16 + l16) * XLD + kt * 32 + lg * 8]);
#pragma unroll
            for (int j = 0; j < 4; ++j) {
                acc1[0][j] = __builtin_amdgcn_mfma_f32_16x16x32_bf16(a[j], xb0, acc1[0][j], 0, 0, 0);
                acc1[1][j] = __builtin_amdgcn_mfma_f32_16x16x32_bf16(a[j], xb1, acc1[1][j], 0, 0, 0);
            }
            __builtin_amdgcn_sched_barrier(0);
            if (kt >= 3 && kt + 2 < 9) {   // refill the just-consumed buffer with kt+2
#pragma unroll
                for (int j = 0; j < 4; ++j)
                    wf[kt & 1][j] = *w1_frag(W1p, kt + 2, w * 4 + j, l);
            }
        }

        // GEMM2 prologue: kt2=0,1 issue now; latency hides under tanh + barrier
#pragma unroll
        for (int j2 = 0; j2 < 2; ++j2) {
            w2b[0][j2] = *w2_frag8(W2p8, 0, w * 2 + j2, l);
            w2b[1][j2] = *w2_frag8(W2p8, 1, w * 2 + j2, l);
        }
        __builtin_amdgcn_sched_barrier(0);

        // tanh + pack hidden into LDS as fp8 (4 f32 -> 1 dword, b32 write)
#pragma unroll
        for (int mt = 0; mt < 2; ++mt)
#pragma unroll
            for (int j = 0; j < 4; ++j) {
                float t0 = tanh_fast(acc1[mt][j][0]), t1 = tanh_fast(acc1[mt][j][1]);
                float t2 = tanh_fast(acc1[mt][j][2]), t3 = tanh_fast(acc1[mt][j][3]);
                int d = 0;
                d = __builtin_amdgcn_cvt_pk_fp8_f32(t0, t1, d, 0);
                d = __builtin_amdgcn_cvt_pk_fp8_f32(t2, t3, d, 1);
                *reinterpret_cast<unsigned int*>(
                    &H8[(mt * 16 + l16) * HLD8 + (w * 4 + j) * 16 + lg * 4]) = (unsigned)d;
            }
        lds_barrier();   // lgkm-only: weight loads stay in flight

        // ---- GEMM2 (fp8): f^T = W2^T (VGPR stream) x hidden^T (LDS), K = 512
        f32x4 acc2[2][2];
#pragma unroll
        for (int mt = 0; mt < 2; ++mt)
#pragma unroll
            for (int j2 = 0; j2 < 2; ++j2)
                acc2[mt][j2] = (f32x4){b2v[j2], b2v[j2], b2v[j2], b2v[j2]};

#pragma unroll
        for (int kt2 = 0; kt2 < 16; ++kt2) {
            u32x2 hb0 = *reinterpret_cast<const u32x2*>(&H8[(0 * 16 + l16) * HLD8 + kt2 * 32 + lg * 8]);
            u32x2 hb1 = *reinterpret_cast<const u32x2*>(&H8[(1 * 16 + l16) * HLD8 + kt2 * 32 + lg * 8]);
#pragma unroll
            for (int j2 = 0; j2 < 2; ++j2) {
                acc2[0][j2] = __builtin_amdgcn_mfma_f32_16x16x32_fp8_fp8(
                    as_i64(w2b[kt2 & 1][j2]), as_i64(hb0), acc2[0][j2], 0, 0, 0);
                acc2[1][j2] = __builtin_amdgcn_mfma_f32_16x16x32_fp8_fp8(
                    as_i64(w2b[kt2 & 1][j2]), as_i64(hb1), acc2[1][j2], 0, 0, 0);
            }
            __builtin_amdgcn_sched_barrier(0);
            if (kt2 + 2 < 16) {   // refill the just-consumed buffer with kt2+2
#pragma unroll
                for (int j2 = 0; j2 < 2; ++j2)
                    w2b[kt2 & 1][j2] = *w2_frag8(W2p8, kt2 + 2, w * 2 + j2, l);
            }
        }

        // z += h * f ; write z back to X (bf16) for next step
#pragma unroll
        for (int mt = 0; mt < 2; ++mt)
#pragma unroll
            for (int j2 = 0; j2 < 2; ++j2)
#pragma unroll
                for (int i = 0; i < 4; ++i)
                    z[mt][j2][i] += hstep[mt] * acc2[mt][j2][i];

        if (t < NSTEPS - 1) {
#pragma unroll
            for (int mt = 0; mt < 2; ++mt)
#pragma unroll
                for (int j2 = 0; j2 < 2; ++j2) {
                    bf16x4 p;
#pragma unroll
                    for (int i = 0; i < 4; ++i) p[i] = f2bf(z[mt][j2][i]);
                    *reinterpret_cast<bf16x4*>(&X[(mt * 16 + l16) * XLD + (w * 2 + j2) * 16 + lg * 4]) = p;
                }
            lds_barrier();
        }
    }

    // final store (f32)
#pragma unroll
    for (int mt = 0; mt < 2; ++mt)
#pragma unroll
        for (int j2 = 0; j2 < 2; ++j2)
            *reinterpret_cast<f32x4*>(
                &out[(row0 + mt * 16 + l16) * LATENT + (w * 2 + j2) * 16 + lg * 4]) = z[mt][j2];
}

extern "C" void kernel_launch(void* const* d_in, const int* in_sizes, int n_in,
                              void* d_out, int out_size, void* d_ws, size_t ws_size,
                              hipStream_t stream) {
    const float* zt = (const float*)d_in[0];
    const float* dtp = (const float*)d_in[1];
    const float* ut = (const float*)d_in[2];
    const float* W1 = (const float*)d_in[3];
    const float* b1 = (const float*)d_in[4];
    const float* W2 = (const float*)d_in[5];
    const float* b2 = (const float*)d_in[6];

    prep_weights<<<136, 256, 0, stream>>>(W1, W2);
    ode_kernel<<<BROWS / BM, 512, 0, stream>>>(zt, dtp, ut, b1, b2, (float*)d_out);
}

// Round 18
// 101.607 us; speedup vs baseline: 1.1568x; 1.0343x over previous
//
#include <hip/hip_runtime.h>
#include <hip/hip_bf16.h>

#define NSTEPS 20
#define BROWS  8192
#define LATENT 256
#define UDIM   16
#define HIDDEN 512
#define BM     32      // rows per block
#define XLD    296     // LDS row stride (bf16) for X
#define HLD8   528     // LDS row stride (BYTES) for fp8 H (2-way free on b32/b64)
#define NKC    3       // W1 kt-tiles cached in LDS (kt = 0..NKC-1)

// packed-weight footprint
#define W1P_SHORTS (9 * 32 * 64 * 8)     // 147456 shorts (294912 B), bf16
#define W2P8_BYTES (16 * 16 * 64 * 8)    // 131072 B, fp8 e4m3

// Packed weights in module-scope device memory; re-packed from immutable
// W1/W2 every call -> deterministic across graph replays.
__device__ __align__(16) short g_Wpack[W1P_SHORTS + W2P8_BYTES / 2];

typedef __attribute__((ext_vector_type(8))) short bf16x8;
typedef __attribute__((ext_vector_type(4))) short bf16x4;
typedef __attribute__((ext_vector_type(4))) float f32x4;
typedef __attribute__((ext_vector_type(2))) unsigned int u32x2;

typedef __attribute__((address_space(1))) const unsigned int gbl_u32;
typedef __attribute__((address_space(3))) unsigned int lds_u32;

__device__ __forceinline__ short f2bf(float x) {
    union { __hip_bfloat16 h; short s; } u;
    u.h = __float2bfloat16(x);
    return u.s;
}

// packed f32x2 -> bf16x2 (RNE), one VALU op instead of ~10 (no builtin; m240)
__device__ __forceinline__ unsigned cvt_pk_bf16(float lo, float hi) {
    unsigned r;
    asm("v_cvt_pk_bf16_f32 %0, %1, %2" : "=v"(r) : "v"(lo), "v"(hi));
    return r;
}

__device__ __forceinline__ long as_i64(u32x2 v) {
    union { u32x2 v; long l; } u; u.v = v; return u.l;
}

__device__ __forceinline__ float tanh_fast(float x) {
    float e = __expf(2.0f * x);
    return 1.0f - 2.0f * __builtin_amdgcn_rcpf(e + 1.0f);
}

// raw barrier: drains LDS ops only; leaves the global-load queue alive
__device__ __forceinline__ void lds_barrier() {
    asm volatile("s_waitcnt lgkmcnt(0)" ::: "memory");
    __builtin_amdgcn_s_barrier();
}

__device__ __forceinline__ const bf16x8* w1_frag(const short* W1p, int kt, int nt, int l) {
    return reinterpret_cast<const bf16x8*>(W1p + ((kt * 32 + nt) * 64 + l) * 8);
}
__device__ __forceinline__ const u32x2* w2_frag8(const unsigned char* W2p8, int kt2, int nt, int l) {
    return reinterpret_cast<const u32x2*>(W2p8 + ((kt2 * 16 + nt) * 64 + l) * 8);
}

// Pack W1 (272x512, K zero-padded to 288) as bf16 and W2 (512x256) as fp8
// e4m3 into per-fragment order: frag(kt,nt): lane l holds
// W[k = kt*32 + (l>>4)*8 + j][n = nt*16 + (l&15)], j=0..7.
__global__ void prep_weights(const float* __restrict__ W1, const float* __restrict__ W2) {
    short* W1p = g_Wpack;
    unsigned char* W2p8 = (unsigned char*)(g_Wpack + W1P_SHORTS);
    int t = blockIdx.x * 256 + threadIdx.x;
    if (t < 9 * 32 * 64) {
        int l = t & 63, f = t >> 6;          // f: 0..287 = kt*32+nt
        int kt = f >> 5, nt = f & 31;
        int k0 = kt * 32 + ((l >> 4) << 3);
        int n = nt * 16 + (l & 15);
        bf16x8 o;
#pragma unroll
        for (int j = 0; j < 8; ++j) {
            int k = k0 + j;
            o[j] = (k < 272) ? f2bf(W1[k * 512 + n]) : (short)0;
        }
        *reinterpret_cast<bf16x8*>(W1p + t * 8) = o;
    } else if (t < 9 * 32 * 64 + 16 * 16 * 64) {
        int t2 = t - 9 * 32 * 64;
        int l = t2 & 63, f = t2 >> 6;        // f: 0..255 = kt*16+nt
        int kt = f >> 4, nt = f & 15;
        int k0 = kt * 32 + ((l >> 4) << 3);
        int n = nt * 16 + (l & 15);
        float v[8];
#pragma unroll
        for (int j = 0; j < 8; ++j) v[j] = W2[(k0 + j) * 256 + n];
        int d0 = 0, d1 = 0;
        d0 = __builtin_amdgcn_cvt_pk_fp8_f32(v[0], v[1], d0, 0);
        d0 = __builtin_amdgcn_cvt_pk_fp8_f32(v[2], v[3], d0, 1);
        d1 = __builtin_amdgcn_cvt_pk_fp8_f32(v[4], v[5], d1, 0);
        d1 = __builtin_amdgcn_cvt_pk_fp8_f32(v[6], v[7], d1, 1);
        *reinterpret_cast<u32x2*>(W2p8 + t2 * 8) = (u32x2){(unsigned)d0, (unsigned)d1};
    }
}

// r18: r17 (W1c cache + bf16 GEMM1 stream + fp8 GEMM2) with:
//  (1) X write-back packed via v_cvt_pk_bf16_f32 (1 op / 2 elems vs ~5/elem
//      RNE sequence) -> ~150 fewer VALU ops/wave/step (VALUBusy was 29%).
//  (2) fp8 W2 stream deepened 2->3-ahead (w2b[3][2], +4 VGPR): 3-iter lead
//      covers the ~200cyc L2 latency that the 2-deep buffer left exposed.
__global__ __launch_bounds__(512, 2) void ode_kernel(
    const float* __restrict__ zt, const float* __restrict__ dtp,
    const float* __restrict__ ut, const float* __restrict__ b1,
    const float* __restrict__ b2, float* __restrict__ out) {
    __shared__ __align__(16) short X[BM * XLD];             // 18,944 B
    __shared__ __align__(16) unsigned char H8[BM * HLD8];   // 16,896 B
    __shared__ __align__(16) short W1c[8][NKC][4][512];     // 98,304 B (134,144 total)

    const short* W1p = g_Wpack;
    const unsigned char* W2p8 = (const unsigned char*)(g_Wpack + W1P_SHORTS);

    const int tid = threadIdx.x;
    const int w = tid >> 6;          // wave 0..7
    const int l = tid & 63;
    const int l16 = l & 15;
    const int lg = l >> 4;           // 0..3
    const int row0 = blockIdx.x * BM;

    // stage the persistent W1 cache FIRST (12 gload_lds per wave, no VGPR dest)
#pragma unroll
    for (int kt = 0; kt < NKC; ++kt)
#pragma unroll
        for (int j = 0; j < 4; ++j)
            __builtin_amdgcn_global_load_lds(
                (gbl_u32*)w1_frag(W1p, kt, w * 4 + j, l),
                (lds_u32*)&W1c[w][kt][j][0], 16, 0, 0);

    float b1v[4], b2v[2];
#pragma unroll
    for (int j = 0; j < 4; ++j) b1v[j] = b1[(w * 4 + j) * 16 + l16];
#pragma unroll
    for (int j = 0; j < 2; ++j) b2v[j] = b2[(w * 2 + j) * 16 + l16];

    float hstep[2];
#pragma unroll
    for (int mt = 0; mt < 2; ++mt)
        hstep[mt] = dtp[row0 + mt * 16 + l16] * (1.0f / NSTEPS);

    f32x4 z[2][2];
#pragma unroll
    for (int mt = 0; mt < 2; ++mt)
#pragma unroll
        for (int j2 = 0; j2 < 2; ++j2)
            z[mt][j2] = *reinterpret_cast<const f32x4*>(
                &zt[(row0 + mt * 16 + l16) * LATENT + (w * 2 + j2) * 16 + lg * 4]);

    {
        int r = tid >> 4, c = tid & 15;   // 512 threads = 32 rows x 16 cols
        X[r * XLD + 256 + c] = f2bf(ut[(row0 + r) * UDIM + c]);
        X[r * XLD + 272 + c] = 0;
    }
#pragma unroll
    for (int mt = 0; mt < 2; ++mt)
#pragma unroll
        for (int j2 = 0; j2 < 2; ++j2) {
            u32x2 p = {cvt_pk_bf16(z[mt][j2][0], z[mt][j2][1]),
                       cvt_pk_bf16(z[mt][j2][2], z[mt][j2][3])};
            *reinterpret_cast<u32x2*>(&X[(mt * 16 + l16) * XLD + (w * 2 + j2) * 16 + lg * 4]) = p;
        }

    // W1c staged + all scalar loads done before the loop
    asm volatile("s_waitcnt vmcnt(0)" ::: "memory");
    lds_barrier();

    bf16x8 wf[2][4];     // streamed-W1 double buffer (kt = 3..8), bf16
    u32x2 w2b[3][2];     // streamed-W2 triple buffer, fp8 (2 VGPR each)

#pragma unroll 1
    for (int t = 0; t < NSTEPS; ++t) {
        // ---- GEMM1: hidden^T = W1^T x X^T, K = 288 (kt 0..2 LDS, 3..8 stream)
        f32x4 acc1[2][4];
#pragma unroll
        for (int mt = 0; mt < 2; ++mt)
#pragma unroll
            for (int j = 0; j < 4; ++j)
                acc1[mt][j] = (f32x4){b1v[j], b1v[j], b1v[j], b1v[j]};

#pragma unroll
        for (int kt = 0; kt < 9; ++kt) {
            if (kt == 0) {   // kt=3's frags: 3-iteration lead (r15 placement)
#pragma unroll
                for (int j = 0; j < 4; ++j) wf[1][j] = *w1_frag(W1p, 3, w * 4 + j, l);
            }
            if (kt == 2) {   // kt=4's frags: 2-iteration lead
#pragma unroll
                for (int j = 0; j < 4; ++j) wf[0][j] = *w1_frag(W1p, 4, w * 4 + j, l);
            }
            __builtin_amdgcn_sched_barrier(0);
            bf16x8 a[4];
            if (kt < NKC) {
#pragma unroll
                for (int j = 0; j < 4; ++j)
                    a[j] = *reinterpret_cast<const bf16x8*>(&W1c[w][kt][j][l * 8]);
            } else {
#pragma unroll
                for (int j = 0; j < 4; ++j) a[j] = wf[kt & 1][j];
            }
            bf16x8 xb0 = *reinterpret_cast<const bf16x8*>(&X[(0 * 16 + l16) * XLD + kt * 32 + lg * 8]);
            bf16x8 xb1 = *reinterpret_cast<const bf16x8*>(&X[(1 * 16 + l16) * XLD + kt * 32 + lg * 8]);
#pragma unroll
            for (int j = 0; j < 4; ++j) {
                acc1[0][j] = __builtin_amdgcn_mfma_f32_16x16x32_bf16(a[j], xb0, acc1[0][j], 0, 0, 0);
                acc1[1][j] = __builtin_amdgcn_mfma_f32_16x16x32_bf16(a[j], xb1, acc1[1][j], 0, 0, 0);
            }
            __builtin_amdgcn_sched_barrier(0);
            if (kt >= 3 && kt + 2 < 9) {   // refill the just-consumed buffer with kt+2
#pragma unroll
                for (int j = 0; j < 4; ++j)
                    wf[kt & 1][j] = *w1_frag(W1p, kt + 2, w * 4 + j, l);
            }
        }

        // GEMM2 prologue: kt2=0,1,2 issue now; latency hides under tanh + barrier
#pragma unroll
        for (int p = 0; p < 3; ++p)
#pragma unroll
            for (int j2 = 0; j2 < 2; ++j2)
                w2b[p][j2] = *w2_frag8(W2p8, p, w * 2 + j2, l);
        __builtin_amdgcn_sched_barrier(0);

        // tanh + pack hidden into LDS as fp8 (4 f32 -> 1 dword, b32 write)
#pragma unroll
        for (int mt = 0; mt < 2; ++mt)
#pragma unroll
            for (int j = 0; j < 4; ++j) {
                float t0 = tanh_fast(acc1[mt][j][0]), t1 = tanh_fast(acc1[mt][j][1]);
                float t2 = tanh_fast(acc1[mt][j][2]), t3 = tanh_fast(acc1[mt][j][3]);
                int d = 0;
                d = __builtin_amdgcn_cvt_pk_fp8_f32(t0, t1, d, 0);
                d = __builtin_amdgcn_cvt_pk_fp8_f32(t2, t3, d, 1);
                *reinterpret_cast<unsigned int*>(
                    &H8[(mt * 16 + l16) * HLD8 + (w * 4 + j) * 16 + lg * 4]) = (unsigned)d;
            }
        lds_barrier();   // lgkm-only: weight loads stay in flight

        // ---- GEMM2 (fp8): f^T = W2^T (VGPR stream, 3-ahead) x hidden^T (LDS), K = 512
        f32x4 acc2[2][2];
#pragma unroll
        for (int mt = 0; mt < 2; ++mt)
#pragma unroll
            for (int j2 = 0; j2 < 2; ++j2)
                acc2[mt][j2] = (f32x4){b2v[j2], b2v[j2], b2v[j2], b2v[j2]};

#pragma unroll
        for (int kt2 = 0; kt2 < 16; ++kt2) {
            u32x2 hb0 = *reinterpret_cast<const u32x2*>(&H8[(0 * 16 + l16) * HLD8 + kt2 * 32 + lg * 8]);
            u32x2 hb1 = *reinterpret_cast<const u32x2*>(&H8[(1 * 16 + l16) * HLD8 + kt2 * 32 + lg * 8]);
#pragma unroll
            for (int j2 = 0; j2 < 2; ++j2) {
                acc2[0][j2] = __builtin_amdgcn_mfma_f32_16x16x32_fp8_fp8(
                    as_i64(w2b[kt2 % 3][j2]), as_i64(hb0), acc2[0][j2], 0, 0, 0);
                acc2[1][j2] = __builtin_amdgcn_mfma_f32_16x16x32_fp8_fp8(
                    as_i64(w2b[kt2 % 3][j2]), as_i64(hb1), acc2[1][j2], 0, 0, 0);
            }
            __builtin_amdgcn_sched_barrier(0);
            if (kt2 + 3 < 16) {   // refill the just-consumed buffer with kt2+3
#pragma unroll
                for (int j2 = 0; j2 < 2; ++j2)
                    w2b[kt2 % 3][j2] = *w2_frag8(W2p8, kt2 + 3, w * 2 + j2, l);
            }
        }

        // z += h * f ; write z back to X (bf16, packed cvt) for next step
#pragma unroll
        for (int mt = 0; mt < 2; ++mt)
#pragma unroll
            for (int j2 = 0; j2 < 2; ++j2)
#pragma unroll
                for (int i = 0; i < 4; ++i)
                    z[mt][j2][i] += hstep[mt] * acc2[mt][j2][i];

        if (t < NSTEPS - 1) {
#pragma unroll
            for (int mt = 0; mt < 2; ++mt)
#pragma unroll
                for (int j2 = 0; j2 < 2; ++j2) {
                    u32x2 p = {cvt_pk_bf16(z[mt][j2][0], z[mt][j2][1]),
                               cvt_pk_bf16(z[mt][j2][2], z[mt][j2][3])};
                    *reinterpret_cast<u32x2*>(&X[(mt * 16 + l16) * XLD + (w * 2 + j2) * 16 + lg * 4]) = p;
                }
            lds_barrier();
        }
    }

    // final store (f32)
#pragma unroll
    for (int mt = 0; mt < 2; ++mt)
#pragma unroll
        for (int j2 = 0; j2 < 2; ++j2)
            *reinterpret_cast<f32x4*>(
                &out[(row0 + mt * 16 + l16) * LATENT + (w * 2 + j2) * 16 + lg * 4]) = z[mt][j2];
}

extern "C" void kernel_launch(void* const* d_in, const int* in_sizes, int n_in,
                              void* d_out, int out_size, void* d_ws, size_t ws_size,
                              hipStream_t stream) {
    const float* zt = (const float*)d_in[0];
    const float* dtp = (const float*)d_in[1];
    const float* ut = (const float*)d_in[2];
    const float* W1 = (const float*)d_in[3];
    const float* b1 = (const float*)d_in[4];
    const float* W2 = (const float*)d_in[5];
    const float* b2 = (const float*)d_in[6];

    prep_weights<<<136, 256, 0, stream>>>(W1, W2);
    ode_kernel<<<BROWS / BM, 512, 0, stream>>>(zt, dtp, ut, b1, b2, (float*)d_out);
}

// Round 19
// 98.346 us; speedup vs baseline: 1.1951x; 1.0332x over previous
//
#include <hip/hip_runtime.h>
#include <hip/hip_bf16.h>

#define NSTEPS 20
#define BROWS  8192
#define LATENT 256
#define UDIM   16
#define HIDDEN 512
#define BM     32      // rows per block
#define XLD    296     // LDS row stride (bf16) for X
#define HLD8   528     // LDS row stride (BYTES) for fp8 H (2-way free on b32/b64)
#define NKC    3       // W1 kt-tiles cached in LDS (kt = 0..NKC-1)
#define NKC2   3       // W2 kt2-tiles cached in LDS (kt2 = 0..NKC2-1)

// packed-weight footprint
#define W1P_SHORTS (9 * 32 * 64 * 8)     // 147456 shorts (294912 B), bf16
#define W2P8_BYTES (16 * 16 * 64 * 8)    // 131072 B, fp8 e4m3

// Packed weights in module-scope device memory; re-packed from immutable
// W1/W2 every call -> deterministic across graph replays.
__device__ __align__(16) short g_Wpack[W1P_SHORTS + W2P8_BYTES / 2];

typedef __attribute__((ext_vector_type(8))) short bf16x8;
typedef __attribute__((ext_vector_type(4))) short bf16x4;
typedef __attribute__((ext_vector_type(4))) float f32x4;
typedef __attribute__((ext_vector_type(2))) unsigned int u32x2;

typedef __attribute__((address_space(1))) const unsigned int gbl_u32;
typedef __attribute__((address_space(3))) unsigned int lds_u32;

__device__ __forceinline__ short f2bf(float x) {
    union { __hip_bfloat16 h; short s; } u;
    u.h = __float2bfloat16(x);
    return u.s;
}

// packed f32x2 -> bf16x2 (RNE), one VALU op instead of ~10 (no builtin; m240)
__device__ __forceinline__ unsigned cvt_pk_bf16(float lo, float hi) {
    unsigned r;
    asm("v_cvt_pk_bf16_f32 %0, %1, %2" : "=v"(r) : "v"(lo), "v"(hi));
    return r;
}

__device__ __forceinline__ long as_i64(u32x2 v) {
    union { u32x2 v; long l; } u; u.v = v; return u.l;
}

__device__ __forceinline__ float tanh_fast(float x) {
    float e = __expf(2.0f * x);
    return 1.0f - 2.0f * __builtin_amdgcn_rcpf(e + 1.0f);
}

// raw barrier: drains LDS ops only; leaves the global-load queue alive
__device__ __forceinline__ void lds_barrier() {
    asm volatile("s_waitcnt lgkmcnt(0)" ::: "memory");
    __builtin_amdgcn_s_barrier();
}

__device__ __forceinline__ const bf16x8* w1_frag(const short* W1p, int kt, int nt, int l) {
    return reinterpret_cast<const bf16x8*>(W1p + ((kt * 32 + nt) * 64 + l) * 8);
}
__device__ __forceinline__ const u32x2* w2_frag8(const unsigned char* W2p8, int kt2, int nt, int l) {
    return reinterpret_cast<const u32x2*>(W2p8 + ((kt2 * 16 + nt) * 64 + l) * 8);
}

// Pack W1 (272x512, K zero-padded to 288) as bf16 and W2 (512x256) as fp8
// e4m3 into per-fragment order: frag(kt,nt): lane l holds
// W[k = kt*32 + (l>>4)*8 + j][n = nt*16 + (l&15)], j=0..7.
__global__ void prep_weights(const float* __restrict__ W1, const float* __restrict__ W2) {
    short* W1p = g_Wpack;
    unsigned char* W2p8 = (unsigned char*)(g_Wpack + W1P_SHORTS);
    int t = blockIdx.x * 256 + threadIdx.x;
    if (t < 9 * 32 * 64) {
        int l = t & 63, f = t >> 6;          // f: 0..287 = kt*32+nt
        int kt = f >> 5, nt = f & 31;
        int k0 = kt * 32 + ((l >> 4) << 3);
        int n = nt * 16 + (l & 15);
        bf16x8 o;
#pragma unroll
        for (int j = 0; j < 8; ++j) {
            int k = k0 + j;
            o[j] = (k < 272) ? f2bf(W1[k * 512 + n]) : (short)0;
        }
        *reinterpret_cast<bf16x8*>(W1p + t * 8) = o;
    } else if (t < 9 * 32 * 64 + 16 * 16 * 64) {
        int t2 = t - 9 * 32 * 64;
        int l = t2 & 63, f = t2 >> 6;        // f: 0..255 = kt*16+nt
        int kt = f >> 4, nt = f & 15;
        int k0 = kt * 32 + ((l >> 4) << 3);
        int n = nt * 16 + (l & 15);
        float v[8];
#pragma unroll
        for (int j = 0; j < 8; ++j) v[j] = W2[(k0 + j) * 256 + n];
        int d0 = 0, d1 = 0;
        d0 = __builtin_amdgcn_cvt_pk_fp8_f32(v[0], v[1], d0, 0);
        d0 = __builtin_amdgcn_cvt_pk_fp8_f32(v[2], v[3], d0, 1);
        d1 = __builtin_amdgcn_cvt_pk_fp8_f32(v[4], v[5], d1, 0);
        d1 = __builtin_amdgcn_cvt_pk_fp8_f32(v[6], v[7], d1, 1);
        *reinterpret_cast<u32x2*>(W2p8 + t2 * 8) = (u32x2){(unsigned)d0, (unsigned)d1};
    }
}

// r19: r18 + W2 kt2=0..2 cached in the remaining 24KB of LDS (wave-private,
// staged once, linear 1KB gload_lds per kt2 since the wave's two frags are
// contiguous in W2p8). Streamed bytes/step/CU: 320 -> 296 KB; GEMM2's first
// 3 iterations are LDS-fed (no post-barrier cold start); pre-tanh prologue
// now issues kt2=3,4,5 with a longer flight window. LDS 158,720 B.
__global__ __launch_bounds__(512, 2) void ode_kernel(
    const float* __restrict__ zt, const float* __restrict__ dtp,
    const float* __restrict__ ut, const float* __restrict__ b1,
    const float* __restrict__ b2, float* __restrict__ out) {
    __shared__ __align__(16) short X[BM * XLD];             // 18,944 B
    __shared__ __align__(16) unsigned char H8[BM * HLD8];   // 16,896 B
    __shared__ __align__(16) short W1c[8][NKC][4][512];     // 98,304 B
    __shared__ __align__(16) unsigned char W2c[8][NKC2][1024]; // 24,576 B (158,720 total)

    const short* W1p = g_Wpack;
    const unsigned char* W2p8 = (const unsigned char*)(g_Wpack + W1P_SHORTS);

    const int tid = threadIdx.x;
    const int w = tid >> 6;          // wave 0..7
    const int l = tid & 63;
    const int l16 = l & 15;
    const int lg = l >> 4;           // 0..3
    const int row0 = blockIdx.x * BM;

    // stage the persistent W1 cache (12 gload_lds per wave, no VGPR dest)
#pragma unroll
    for (int kt = 0; kt < NKC; ++kt)
#pragma unroll
        for (int j = 0; j < 4; ++j)
            __builtin_amdgcn_global_load_lds(
                (gbl_u32*)w1_frag(W1p, kt, w * 4 + j, l),
                (lds_u32*)&W1c[w][kt][j][0], 16, 0, 0);
    // stage the persistent W2 cache (3 gload_lds per wave; wave's two frags
    // per kt2 are contiguous 1KB in W2p8 -> linear lane*16 copy)
#pragma unroll
    for (int kt2 = 0; kt2 < NKC2; ++kt2)
        __builtin_amdgcn_global_load_lds(
            (gbl_u32*)(W2p8 + ((kt2 * 16 + w * 2) * 64) * 8 + l * 16),
            (lds_u32*)&W2c[w][kt2][0], 16, 0, 0);

    float b1v[4], b2v[2];
#pragma unroll
    for (int j = 0; j < 4; ++j) b1v[j] = b1[(w * 4 + j) * 16 + l16];
#pragma unroll
    for (int j = 0; j < 2; ++j) b2v[j] = b2[(w * 2 + j) * 16 + l16];

    float hstep[2];
#pragma unroll
    for (int mt = 0; mt < 2; ++mt)
        hstep[mt] = dtp[row0 + mt * 16 + l16] * (1.0f / NSTEPS);

    f32x4 z[2][2];
#pragma unroll
    for (int mt = 0; mt < 2; ++mt)
#pragma unroll
        for (int j2 = 0; j2 < 2; ++j2)
            z[mt][j2] = *reinterpret_cast<const f32x4*>(
                &zt[(row0 + mt * 16 + l16) * LATENT + (w * 2 + j2) * 16 + lg * 4]);

    {
        int r = tid >> 4, c = tid & 15;   // 512 threads = 32 rows x 16 cols
        X[r * XLD + 256 + c] = f2bf(ut[(row0 + r) * UDIM + c]);
        X[r * XLD + 272 + c] = 0;
    }
#pragma unroll
    for (int mt = 0; mt < 2; ++mt)
#pragma unroll
        for (int j2 = 0; j2 < 2; ++j2) {
            u32x2 p = {cvt_pk_bf16(z[mt][j2][0], z[mt][j2][1]),
                       cvt_pk_bf16(z[mt][j2][2], z[mt][j2][3])};
            *reinterpret_cast<u32x2*>(&X[(mt * 16 + l16) * XLD + (w * 2 + j2) * 16 + lg * 4]) = p;
        }

    // W1c/W2c staged + all scalar loads done before the loop
    asm volatile("s_waitcnt vmcnt(0)" ::: "memory");
    lds_barrier();

    bf16x8 wf[2][4];     // streamed-W1 double buffer (kt = 3..8), bf16
    u32x2 w2b[3][2];     // streamed-W2 triple buffer (kt2 = 3..15), fp8

#pragma unroll 1
    for (int t = 0; t < NSTEPS; ++t) {
        // ---- GEMM1: hidden^T = W1^T x X^T, K = 288 (kt 0..2 LDS, 3..8 stream)
        f32x4 acc1[2][4];
#pragma unroll
        for (int mt = 0; mt < 2; ++mt)
#pragma unroll
            for (int j = 0; j < 4; ++j)
                acc1[mt][j] = (f32x4){b1v[j], b1v[j], b1v[j], b1v[j]};

#pragma unroll
        for (int kt = 0; kt < 9; ++kt) {
            if (kt == 0) {   // kt=3's frags: 3-iteration lead (r15 placement)
#pragma unroll
                for (int j = 0; j < 4; ++j) wf[1][j] = *w1_frag(W1p, 3, w * 4 + j, l);
            }
            if (kt == 2) {   // kt=4's frags: 2-iteration lead
#pragma unroll
                for (int j = 0; j < 4; ++j) wf[0][j] = *w1_frag(W1p, 4, w * 4 + j, l);
            }
            __builtin_amdgcn_sched_barrier(0);
            bf16x8 a[4];
            if (kt < NKC) {
#pragma unroll
                for (int j = 0; j < 4; ++j)
                    a[j] = *reinterpret_cast<const bf16x8*>(&W1c[w][kt][j][l * 8]);
            } else {
#pragma unroll
                for (int j = 0; j < 4; ++j) a[j] = wf[kt & 1][j];
            }
            bf16x8 xb0 = *reinterpret_cast<const bf16x8*>(&X[(0 * 16 + l16) * XLD + kt * 32 + lg * 8]);
            bf16x8 xb1 = *reinterpret_cast<const bf16x8*>(&X[(1 * 16 + l16) * XLD + kt * 32 + lg * 8]);
#pragma unroll
            for (int j = 0; j < 4; ++j) {
                acc1[0][j] = __builtin_amdgcn_mfma_f32_16x16x32_bf16(a[j], xb0, acc1[0][j], 0, 0, 0);
                acc1[1][j] = __builtin_amdgcn_mfma_f32_16x16x32_bf16(a[j], xb1, acc1[1][j], 0, 0, 0);
            }
            __builtin_amdgcn_sched_barrier(0);
            if (kt >= 3 && kt + 2 < 9) {   // refill the just-consumed buffer with kt+2
#pragma unroll
                for (int j = 0; j < 4; ++j)
                    wf[kt & 1][j] = *w1_frag(W1p, kt + 2, w * 4 + j, l);
            }
        }

        // GEMM2 prologue: kt2=3,4,5 issue now; latency hides under tanh + barrier
#pragma unroll
        for (int p = 3; p < 6; ++p)
#pragma unroll
            for (int j2 = 0; j2 < 2; ++j2)
                w2b[p % 3][j2] = *w2_frag8(W2p8, p, w * 2 + j2, l);
        __builtin_amdgcn_sched_barrier(0);

        // tanh + pack hidden into LDS as fp8 (4 f32 -> 1 dword, b32 write)
#pragma unroll
        for (int mt = 0; mt < 2; ++mt)
#pragma unroll
            for (int j = 0; j < 4; ++j) {
                float t0 = tanh_fast(acc1[mt][j][0]), t1 = tanh_fast(acc1[mt][j][1]);
                float t2 = tanh_fast(acc1[mt][j][2]), t3 = tanh_fast(acc1[mt][j][3]);
                int d = 0;
                d = __builtin_amdgcn_cvt_pk_fp8_f32(t0, t1, d, 0);
                d = __builtin_amdgcn_cvt_pk_fp8_f32(t2, t3, d, 1);
                *reinterpret_cast<unsigned int*>(
                    &H8[(mt * 16 + l16) * HLD8 + (w * 4 + j) * 16 + lg * 4]) = (unsigned)d;
            }
        lds_barrier();   // lgkm-only: weight loads stay in flight

        // ---- GEMM2 (fp8): f^T = W2^T x hidden^T, K = 512 (kt2 0..2 LDS, 3..15 stream)
        f32x4 acc2[2][2];
#pragma unroll
        for (int mt = 0; mt < 2; ++mt)
#pragma unroll
            for (int j2 = 0; j2 < 2; ++j2)
                acc2[mt][j2] = (f32x4){b2v[j2], b2v[j2], b2v[j2], b2v[j2]};

#pragma unroll
        for (int kt2 = 0; kt2 < 16; ++kt2) {
            u32x2 a2[2];
            if (kt2 < NKC2) {
#pragma unroll
                for (int j2 = 0; j2 < 2; ++j2)
                    a2[j2] = *reinterpret_cast<const u32x2*>(&W2c[w][kt2][j2 * 512 + l * 8]);
            } else {
#pragma unroll
                for (int j2 = 0; j2 < 2; ++j2) a2[j2] = w2b[kt2 % 3][j2];
            }
            u32x2 hb0 = *reinterpret_cast<const u32x2*>(&H8[(0 * 16 + l16) * HLD8 + kt2 * 32 + lg * 8]);
            u32x2 hb1 = *reinterpret_cast<const u32x2*>(&H8[(1 * 16 + l16) * HLD8 + kt2 * 32 + lg * 8]);
#pragma unroll
            for (int j2 = 0; j2 < 2; ++j2) {
                acc2[0][j2] = __builtin_amdgcn_mfma_f32_16x16x32_fp8_fp8(
                    as_i64(a2[j2]), as_i64(hb0), acc2[0][j2], 0, 0, 0);
                acc2[1][j2] = __builtin_amdgcn_mfma_f32_16x16x32_fp8_fp8(
                    as_i64(a2[j2]), as_i64(hb1), acc2[1][j2], 0, 0, 0);
            }
            __builtin_amdgcn_sched_barrier(0);
            if (kt2 >= 3 && kt2 + 3 < 16) {   // refill the just-consumed buffer with kt2+3
#pragma unroll
                for (int j2 = 0; j2 < 2; ++j2)
                    w2b[kt2 % 3][j2] = *w2_frag8(W2p8, kt2 + 3, w * 2 + j2, l);
            }
        }

        // z += h * f ; write z back to X (bf16, packed cvt) for next step
#pragma unroll
        for (int mt = 0; mt < 2; ++mt)
#pragma unroll
            for (int j2 = 0; j2 < 2; ++j2)
#pragma unroll
                for (int i = 0; i < 4; ++i)
                    z[mt][j2][i] += hstep[mt] * acc2[mt][j2][i];

        if (t < NSTEPS - 1) {
#pragma unroll
            for (int mt = 0; mt < 2; ++mt)
#pragma unroll
                for (int j2 = 0; j2 < 2; ++j2) {
                    u32x2 p = {cvt_pk_bf16(z[mt][j2][0], z[mt][j2][1]),
                               cvt_pk_bf16(z[mt][j2][2], z[mt][j2][3])};
                    *reinterpret_cast<u32x2*>(&X[(mt * 16 + l16) * XLD + (w * 2 + j2) * 16 + lg * 4]) = p;
                }
            lds_barrier();
        }
    }

    // final store (f32)
#pragma unroll
    for (int mt = 0; mt < 2; ++mt)
#pragma unroll
        for (int j2 = 0; j2 < 2; ++j2)
            *reinterpret_cast<f32x4*>(
                &out[(row0 + mt * 16 + l16) * LATENT + (w * 2 + j2) * 16 + lg * 4]) = z[mt][j2];
}

extern "C" void kernel_launch(void* const* d_in, const int* in_sizes, int n_in,
                              void* d_out, int out_size, void* d_ws, size_t ws_size,
                              hipStream_t stream) {
    const float* zt = (const float*)d_in[0];
    const float* dtp = (const float*)d_in[1];
    const float* ut = (const float*)d_in[2];
    const float* W1 = (const float*)d_in[3];
    const float* b1 = (const float*)d_in[4];
    const float* W2 = (const float*)d_in[5];
    const float* b2 = (const float*)d_in[6];

    prep_weights<<<136, 256, 0, stream>>>(W1, W2);
    ode_kernel<<<BROWS / BM, 512, 0, stream>>>(zt, dtp, ut, b1, b2, (float*)d_out);
}

// Round 20
// 95.725 us; speedup vs baseline: 1.2279x; 1.0274x over previous
//
#include <hip/hip_runtime.h>
#include <hip/hip_bf16.h>

#define NSTEPS 20
#define BROWS  8192
#define LATENT 256
#define UDIM   16
#define HIDDEN 512
#define BM     32      // rows per block
#define XLD    296     // LDS row stride (bf16) for X
#define HLD8   528     // LDS row stride (BYTES) for fp8 H
#define NKC    3       // W1 kt-tiles cached in LDS (kt = 0..NKC-1)
#define NKC2   3       // W2 kt2-tiles cached in LDS (kt2 = 0..NKC2-1)

// packed-weight footprint
#define W1P_SHORTS (9 * 32 * 64 * 8)     // 147456 shorts (294912 B), bf16
#define W2P8_BYTES (16 * 16 * 64 * 8)    // 131072 B, fp8 e4m3

// Packed weights in module-scope device memory; re-packed from immutable
// W1/W2 every call -> deterministic across graph replays.
__device__ __align__(16) short g_Wpack[W1P_SHORTS + W2P8_BYTES / 2];

typedef __attribute__((ext_vector_type(8))) short bf16x8;
typedef __attribute__((ext_vector_type(4))) short bf16x4;
typedef __attribute__((ext_vector_type(4))) float f32x4;
typedef __attribute__((ext_vector_type(2))) unsigned int u32x2;

typedef __attribute__((address_space(1))) const unsigned int gbl_u32;
typedef __attribute__((address_space(3))) unsigned int lds_u32;

__device__ __forceinline__ short f2bf(float x) {
    union { __hip_bfloat16 h; short s; } u;
    u.h = __float2bfloat16(x);
    return u.s;
}

// packed f32x2 -> bf16x2 (RNE), one VALU op instead of ~10 (no builtin; m240)
__device__ __forceinline__ unsigned cvt_pk_bf16(float lo, float hi) {
    unsigned r;
    asm("v_cvt_pk_bf16_f32 %0, %1, %2" : "=v"(r) : "v"(lo), "v"(hi));
    return r;
}

__device__ __forceinline__ long as_i64(u32x2 v) {
    union { u32x2 v; long l; } u; u.v = v; return u.l;
}

// tanh(x) = 1 - 2/(2^(x*2*log2e)+1); one constant mul + v_exp_f32.
// x->+inf: e2=inf -> 1; x->-inf: e2=0 -> -1.
__device__ __forceinline__ float tanh_fast(float x) {
    float e2 = __builtin_amdgcn_exp2f(x * 2.8853900817779268f);
    return 1.0f - 2.0f * __builtin_amdgcn_rcpf(e2 + 1.0f);
}

// raw barrier: drains LDS ops only; leaves the global-load queue alive
__device__ __forceinline__ void lds_barrier() {
    asm volatile("s_waitcnt lgkmcnt(0)" ::: "memory");
    __builtin_amdgcn_s_barrier();
}

__device__ __forceinline__ const bf16x8* w1_frag(const short* W1p, int kt, int nt, int l) {
    return reinterpret_cast<const bf16x8*>(W1p + ((kt * 32 + nt) * 64 + l) * 8);
}
__device__ __forceinline__ const u32x2* w2_frag8(const unsigned char* W2p8, int kt2, int nt, int l) {
    return reinterpret_cast<const u32x2*>(W2p8 + ((kt2 * 16 + nt) * 64 + l) * 8);
}

// Pack W1 (272x512, K zero-padded to 288) as bf16 and W2 (512x256) as fp8
// e4m3 into per-fragment order: frag(kt,nt): lane l holds
// W[k = kt*32 + (l>>4)*8 + j][n = nt*16 + (l&15)], j=0..7.
__global__ void prep_weights(const float* __restrict__ W1, const float* __restrict__ W2) {
    short* W1p = g_Wpack;
    unsigned char* W2p8 = (unsigned char*)(g_Wpack + W1P_SHORTS);
    int t = blockIdx.x * 256 + threadIdx.x;
    if (t < 9 * 32 * 64) {
        int l = t & 63, f = t >> 6;          // f: 0..287 = kt*32+nt
        int kt = f >> 5, nt = f & 31;
        int k0 = kt * 32 + ((l >> 4) << 3);
        int n = nt * 16 + (l & 15);
        bf16x8 o;
#pragma unroll
        for (int j = 0; j < 8; ++j) {
            int k = k0 + j;
            o[j] = (k < 272) ? f2bf(W1[k * 512 + n]) : (short)0;
        }
        *reinterpret_cast<bf16x8*>(W1p + t * 8) = o;
    } else if (t < 9 * 32 * 64 + 16 * 16 * 64) {
        int t2 = t - 9 * 32 * 64;
        int l = t2 & 63, f = t2 >> 6;        // f: 0..255 = kt*16+nt
        int kt = f >> 4, nt = f & 15;
        int k0 = kt * 32 + ((l >> 4) << 3);
        int n = nt * 16 + (l & 15);
        float v[8];
#pragma unroll
        for (int j = 0; j < 8; ++j) v[j] = W2[(k0 + j) * 256 + n];
        int d0 = 0, d1 = 0;
        d0 = __builtin_amdgcn_cvt_pk_fp8_f32(v[0], v[1], d0, 0);
        d0 = __builtin_amdgcn_cvt_pk_fp8_f32(v[2], v[3], d0, 1);
        d1 = __builtin_amdgcn_cvt_pk_fp8_f32(v[4], v[5], d1, 0);
        d1 = __builtin_amdgcn_cvt_pk_fp8_f32(v[6], v[7], d1, 1);
        *reinterpret_cast<u32x2*>(W2p8 + t2 * 8) = (u32x2){(unsigned)d0, (unsigned)d1};
    }
}

// r20: r19 (W1c+W2c LDS caches, bf16 GEMM1 + fp8 GEMM2 VGPR streams) with:
//  (1) w2b deepened 3->4 (prologue kt2=3..6 pre-tanh; refills 4-ahead) so the
//      fp8 stream never exposes L2 latency across GEMM2's span. +4 VGPR.
//  (2) exp2-direct tanh (one fused-constant mul instead of two).
__global__ __launch_bounds__(512, 2) void ode_kernel(
    const float* __restrict__ zt, const float* __restrict__ dtp,
    const float* __restrict__ ut, const float* __restrict__ b1,
    const float* __restrict__ b2, float* __restrict__ out) {
    __shared__ __align__(16) short X[BM * XLD];             // 18,944 B
    __shared__ __align__(16) unsigned char H8[BM * HLD8];   // 16,896 B
    __shared__ __align__(16) short W1c[8][NKC][4][512];     // 98,304 B
    __shared__ __align__(16) unsigned char W2c[8][NKC2][1024]; // 24,576 B (158,720 total)

    const short* W1p = g_Wpack;
    const unsigned char* W2p8 = (const unsigned char*)(g_Wpack + W1P_SHORTS);

    const int tid = threadIdx.x;
    const int w = tid >> 6;          // wave 0..7
    const int l = tid & 63;
    const int l16 = l & 15;
    const int lg = l >> 4;           // 0..3
    const int row0 = blockIdx.x * BM;

    // stage the persistent W1 cache (12 gload_lds per wave, no VGPR dest)
#pragma unroll
    for (int kt = 0; kt < NKC; ++kt)
#pragma unroll
        for (int j = 0; j < 4; ++j)
            __builtin_amdgcn_global_load_lds(
                (gbl_u32*)w1_frag(W1p, kt, w * 4 + j, l),
                (lds_u32*)&W1c[w][kt][j][0], 16, 0, 0);
    // stage the persistent W2 cache (3 gload_lds per wave; wave's two frags
    // per kt2 are contiguous 1KB in W2p8 -> linear lane*16 copy)
#pragma unroll
    for (int kt2 = 0; kt2 < NKC2; ++kt2)
        __builtin_amdgcn_global_load_lds(
            (gbl_u32*)(W2p8 + ((kt2 * 16 + w * 2) * 64) * 8 + l * 16),
            (lds_u32*)&W2c[w][kt2][0], 16, 0, 0);

    float b1v[4], b2v[2];
#pragma unroll
    for (int j = 0; j < 4; ++j) b1v[j] = b1[(w * 4 + j) * 16 + l16];
#pragma unroll
    for (int j = 0; j < 2; ++j) b2v[j] = b2[(w * 2 + j) * 16 + l16];

    float hstep[2];
#pragma unroll
    for (int mt = 0; mt < 2; ++mt)
        hstep[mt] = dtp[row0 + mt * 16 + l16] * (1.0f / NSTEPS);

    f32x4 z[2][2];
#pragma unroll
    for (int mt = 0; mt < 2; ++mt)
#pragma unroll
        for (int j2 = 0; j2 < 2; ++j2)
            z[mt][j2] = *reinterpret_cast<const f32x4*>(
                &zt[(row0 + mt * 16 + l16) * LATENT + (w * 2 + j2) * 16 + lg * 4]);

    {
        int r = tid >> 4, c = tid & 15;   // 512 threads = 32 rows x 16 cols
        X[r * XLD + 256 + c] = f2bf(ut[(row0 + r) * UDIM + c]);
        X[r * XLD + 272 + c] = 0;
    }
#pragma unroll
    for (int mt = 0; mt < 2; ++mt)
#pragma unroll
        for (int j2 = 0; j2 < 2; ++j2) {
            u32x2 p = {cvt_pk_bf16(z[mt][j2][0], z[mt][j2][1]),
                       cvt_pk_bf16(z[mt][j2][2], z[mt][j2][3])};
            *reinterpret_cast<u32x2*>(&X[(mt * 16 + l16) * XLD + (w * 2 + j2) * 16 + lg * 4]) = p;
        }

    // W1c/W2c staged + all scalar loads done before the loop
    asm volatile("s_waitcnt vmcnt(0)" ::: "memory");
    lds_barrier();

    bf16x8 wf[2][4];     // streamed-W1 double buffer (kt = 3..8), bf16
    u32x2 w2b[4][2];     // streamed-W2 quad buffer (kt2 = 3..15), fp8

#pragma unroll 1
    for (int t = 0; t < NSTEPS; ++t) {
        // ---- GEMM1: hidden^T = W1^T x X^T, K = 288 (kt 0..2 LDS, 3..8 stream)
        f32x4 acc1[2][4];
#pragma unroll
        for (int mt = 0; mt < 2; ++mt)
#pragma unroll
            for (int j = 0; j < 4; ++j)
                acc1[mt][j] = (f32x4){b1v[j], b1v[j], b1v[j], b1v[j]};

#pragma unroll
        for (int kt = 0; kt < 9; ++kt) {
            if (kt == 0) {   // kt=3's frags: 3-iteration lead (r15 placement)
#pragma unroll
                for (int j = 0; j < 4; ++j) wf[1][j] = *w1_frag(W1p, 3, w * 4 + j, l);
            }
            if (kt == 2) {   // kt=4's frags: 2-iteration lead
#pragma unroll
                for (int j = 0; j < 4; ++j) wf[0][j] = *w1_frag(W1p, 4, w * 4 + j, l);
            }
            __builtin_amdgcn_sched_barrier(0);
            bf16x8 a[4];
            if (kt < NKC) {
#pragma unroll
                for (int j = 0; j < 4; ++j)
                    a[j] = *reinterpret_cast<const bf16x8*>(&W1c[w][kt][j][l * 8]);
            } else {
#pragma unroll
                for (int j = 0; j < 4; ++j) a[j] = wf[kt & 1][j];
            }
            bf16x8 xb0 = *reinterpret_cast<const bf16x8*>(&X[(0 * 16 + l16) * XLD + kt * 32 + lg * 8]);
            bf16x8 xb1 = *reinterpret_cast<const bf16x8*>(&X[(1 * 16 + l16) * XLD + kt * 32 + lg * 8]);
#pragma unroll
            for (int j = 0; j < 4; ++j) {
                acc1[0][j] = __builtin_amdgcn_mfma_f32_16x16x32_bf16(a[j], xb0, acc1[0][j], 0, 0, 0);
                acc1[1][j] = __builtin_amdgcn_mfma_f32_16x16x32_bf16(a[j], xb1, acc1[1][j], 0, 0, 0);
            }
            __builtin_amdgcn_sched_barrier(0);
            if (kt >= 3 && kt + 2 < 9) {   // refill the just-consumed buffer with kt+2
#pragma unroll
                for (int j = 0; j < 4; ++j)
                    wf[kt & 1][j] = *w1_frag(W1p, kt + 2, w * 4 + j, l);
            }
        }

        // GEMM2 prologue: kt2=3..6 issue now; latency hides under tanh + barrier
#pragma unroll
        for (int p = 3; p < 7; ++p)
#pragma unroll
            for (int j2 = 0; j2 < 2; ++j2)
                w2b[p % 4][j2] = *w2_frag8(W2p8, p, w * 2 + j2, l);
        __builtin_amdgcn_sched_barrier(0);

        // tanh + pack hidden into LDS as fp8 (4 f32 -> 1 dword, b32 write)
#pragma unroll
        for (int mt = 0; mt < 2; ++mt)
#pragma unroll
            for (int j = 0; j < 4; ++j) {
                float t0 = tanh_fast(acc1[mt][j][0]), t1 = tanh_fast(acc1[mt][j][1]);
                float t2 = tanh_fast(acc1[mt][j][2]), t3 = tanh_fast(acc1[mt][j][3]);
                int d = 0;
                d = __builtin_amdgcn_cvt_pk_fp8_f32(t0, t1, d, 0);
                d = __builtin_amdgcn_cvt_pk_fp8_f32(t2, t3, d, 1);
                *reinterpret_cast<unsigned int*>(
                    &H8[(mt * 16 + l16) * HLD8 + (w * 4 + j) * 16 + lg * 4]) = (unsigned)d;
            }
        lds_barrier();   // lgkm-only: weight loads stay in flight

        // ---- GEMM2 (fp8): f^T = W2^T x hidden^T, K = 512 (kt2 0..2 LDS, 3..15 stream)
        f32x4 acc2[2][2];
#pragma unroll
        for (int mt = 0; mt < 2; ++mt)
#pragma unroll
            for (int j2 = 0; j2 < 2; ++j2)
                acc2[mt][j2] = (f32x4){b2v[j2], b2v[j2], b2v[j2], b2v[j2]};

#pragma unroll
        for (int kt2 = 0; kt2 < 16; ++kt2) {
            u32x2 a2[2];
            if (kt2 < NKC2) {
#pragma unroll
                for (int j2 = 0; j2 < 2; ++j2)
                    a2[j2] = *reinterpret_cast<const u32x2*>(&W2c[w][kt2][j2 * 512 + l * 8]);
            } else {
#pragma unroll
                for (int j2 = 0; j2 < 2; ++j2) a2[j2] = w2b[kt2 % 4][j2];
            }
            u32x2 hb0 = *reinterpret_cast<const u32x2*>(&H8[(0 * 16 + l16) * HLD8 + kt2 * 32 + lg * 8]);
            u32x2 hb1 = *reinterpret_cast<const u32x2*>(&H8[(1 * 16 + l16) * HLD8 + kt2 * 32 + lg * 8]);
#pragma unroll
            for (int j2 = 0; j2 < 2; ++j2) {
                acc2[0][j2] = __builtin_amdgcn_mfma_f32_16x16x32_fp8_fp8(
                    as_i64(a2[j2]), as_i64(hb0), acc2[0][j2], 0, 0, 0);
                acc2[1][j2] = __builtin_amdgcn_mfma_f32_16x16x32_fp8_fp8(
                    as_i64(a2[j2]), as_i64(hb1), acc2[1][j2], 0, 0, 0);
            }
            __builtin_amdgcn_sched_barrier(0);
            if (kt2 >= 3 && kt2 + 4 < 16) {   // refill the just-consumed buffer with kt2+4
#pragma unroll
                for (int j2 = 0; j2 < 2; ++j2)
                    w2b[kt2 % 4][j2] = *w2_frag8(W2p8, kt2 + 4, w * 2 + j2, l);
            }
        }

        // z += h * f ; write z back to X (bf16, packed cvt) for next step
#pragma unroll
        for (int mt = 0; mt < 2; ++mt)
#pragma unroll
            for (int j2 = 0; j2 < 2; ++j2)
#pragma unroll
                for (int i = 0; i < 4; ++i)
                    z[mt][j2][i] += hstep[mt] * acc2[mt][j2][i];

        if (t < NSTEPS - 1) {
#pragma unroll
            for (int mt = 0; mt < 2; ++mt)
#pragma unroll
                for (int j2 = 0; j2 < 2; ++j2) {
                    u32x2 p = {cvt_pk_bf16(z[mt][j2][0], z[mt][j2][1]),
                               cvt_pk_bf16(z[mt][j2][2], z[mt][j2][3])};
                    *reinterpret_cast<u32x2*>(&X[(mt * 16 + l16) * XLD + (w * 2 + j2) * 16 + lg * 4]) = p;
                }
            lds_barrier();
        }
    }

    // final store (f32)
#pragma unroll
    for (int mt = 0; mt < 2; ++mt)
#pragma unroll
        for (int j2 = 0; j2 < 2; ++j2)
            *reinterpret_cast<f32x4*>(
                &out[(row0 + mt * 16 + l16) * LATENT + (w * 2 + j2) * 16 + lg * 4]) = z[mt][j2];
}

extern "C" void kernel_launch(void* const* d_in, const int* in_sizes, int n_in,
                              void* d_out, int out_size, void* d_ws, size_t ws_size,
                              hipStream_t stream) {
    const float* zt = (const float*)d_in[0];
    const float* dtp = (const float*)d_in[1];
    const float* ut = (const float*)d_in[2];
    const float* W1 = (const float*)d_in[3];
    const float* b1 = (const float*)d_in[4];
    const float* W2 = (const float*)d_in[5];
    const float* b2 = (const float*)d_in[6];

    prep_weights<<<136, 256, 0, stream>>>(W1, W2);
    ode_kernel<<<BROWS / BM, 512, 0, stream>>>(zt, dtp, ut, b1, b2, (float*)d_out);
}